// Round 12
// baseline (85.801 us; speedup 1.0000x reference)
//
#include <hip/hip_runtime.h>
#include <hip/hip_bf16.h>
#include <stdint.h>

typedef __attribute__((ext_vector_type(4))) float f32x4;
typedef __attribute__((ext_vector_type(4))) unsigned int u32x4;
typedef __attribute__((ext_vector_type(8))) short short8;

#define MFMA16(a, b, c) __builtin_amdgcn_mfma_f32_16x16x32_bf16((a), (b), (c), 0, 0, 0)

__device__ __forceinline__ uint16_t f2bf(float f) {
  __hip_bfloat16 h = __float2bfloat16(f);
  return __builtin_bit_cast(uint16_t, h);
}

// v_rcp_f32-based sigmoid: rcp rel-err ~1ulp << bf16 rounding of every consumer.
__device__ __forceinline__ float fast_sigmoid(float v) {
  return __builtin_amdgcn_rcpf(1.f + __expf(-v));
}

__device__ __forceinline__ short8 cvt8(f32x4 a, f32x4 b) {
  short8 r;
  r[0] = (short)f2bf(a[0]); r[1] = (short)f2bf(a[1]);
  r[2] = (short)f2bf(a[2]); r[3] = (short)f2bf(a[3]);
  r[4] = (short)f2bf(b[0]); r[5] = (short)f2bf(b[1]);
  r[6] = (short)f2bf(b[2]); r[7] = (short)f2bf(b[3]);
  return r;
}

__device__ __forceinline__ uint32_t pk2(float a, float b) {
  return (uint32_t)f2bf(a) | ((uint32_t)f2bf(b) << 16);
}

// XOR-swizzled byte offset into row-major [rows][RB bytes] LDS tile (16B slots).
template <int RB>
__device__ __forceinline__ int swzoff(int row, int bcol) {
  constexpr int SLM = (((RB / 16) < 8 ? (RB / 16) : 8)) - 1;
  return row * RB + (bcol ^ ((row & SLM) << 4));
}

// A-fragment (16x32 bf16) from swizzled bf16 LDS tile.
template <int RB>
__device__ __forceinline__ short8 lds_a(const uint16_t* buf, int row0, int k0, int lane) {
  int r = row0 + (lane & 15);
  int bcol = (k0 + ((lane >> 4) << 3)) * 2;
  u32x4 raw = *(const u32x4*)((const char*)buf + swzoff<RB>(r, bcol));
  return __builtin_bit_cast(short8, raw);
}

// Fragment from row-major fp32 M[ld] (coalesced 16-row pattern)
__device__ __forceinline__ short8 load_frag_f32(const float* M, int ld, int r0, int k0, int lane) {
  const float* p = M + (size_t)(r0 + (lane & 15)) * ld + (k0 + ((lane >> 4) << 3));
  f32x4 a = *(const f32x4*)p;
  f32x4 b = *(const f32x4*)(p + 4);
  return cvt8(a, b);
}

// Packed-path B-fragment: one coalesced 16B load from pre-packed d_ws
__device__ __forceinline__ short8 load_b_pk(const char* base, int f, int lane) {
  u32x4 raw = *(const u32x4*)(base + (((size_t)f * 64 + lane) << 4));
  return __builtin_bit_cast(short8, raw);
}

template <bool P>
__device__ __forceinline__ short8 bfrag(const char* wp, const float* W, int K,
                                        int f0, int ntg, int KT, int kt, int lane) {
  if constexpr (P) {
    return load_b_pk(wp, f0 + ntg * KT + kt, lane);
  } else {
    return load_frag_f32(W, K, ntg * 16, kt * 32, lane);
  }
}

// ---- weight pre-pack: 372 fragments x (64 lanes x 16B) = 372 KB in d_ws ----
__global__ void pack_kernel(const float* __restrict__ w1, const float* __restrict__ w2,
                            const float* __restrict__ w3, const float* __restrict__ w4,
                            const float* __restrict__ w5, char* __restrict__ ws) {
  int b = blockIdx.x, lane = threadIdx.x;
  const float* W;
  int K, f0;
  if (b < 256)      { W = w1; K = 512; f0 = 0; }
  else if (b < 320) { W = w2; K = 256; f0 = 256; }
  else if (b < 336) { W = w3; K = 128; f0 = 320; }
  else if (b < 340) { W = w4; K = 64;  f0 = 336; }
  else              { W = w5; K = 32;  f0 = 340; }
  int f = b - f0;
  int KT = K / 32;
  int nt = f / KT, kt = f % KT;
  short8 r = load_frag_f32(W, K, nt * 16, kt * 32, lane);
  *(u32x4*)(ws + (((size_t)b * 64 + lane) << 4)) = __builtin_bit_cast(u32x4, r);
}

// ============================================================================
// SPLIT PATH (packed-only; requires ws >= 512KB + 32MB h1 buffer).
// Rationale: the fused kernel's per-block serial chain {read burst -> L1 MFMA
// -> tail VALU -> write burst} caps chip HBM duty at ~35% (2.2/6.3 TB/s,
// rounds 0-11). Two homogeneous streaming passes let reads/compute (A) and
// writes (B) each overlap chip-wide. h1 crosses as per-block 16KB bf16 pages
// holding the SWIZZLED LDS image verbatim -> B restages bytes 1:1 and
// lds_a<512> works unchanged.
// ============================================================================

// Kernel A: L1 only. r11's one-shot stage + free-run, epilogue -> H1 LDS ->
// coalesced 16KB page store.
__global__ __launch_bounds__(256, 3) void l1_kernel(
    const float* __restrict__ x, const float* __restrict__ b1,
    const char* __restrict__ wp, char* __restrict__ h1g) {
  __shared__ __align__(16) char smem[32 * 1024];
  uint16_t* XB = (uint16_t*)smem;  // [32][512] bf16, RB=1024
  uint16_t* H1 = (uint16_t*)smem;  // [32][256] bf16, RB=512 (overlays XB)

  const int tid = threadIdx.x;
  const int lane = tid & 63;
  const int wid = tid >> 6;
  const int row0 = blockIdx.x * 32;
  const int lr = (lane >> 4) << 2;
  const int lc = lane & 15;

  // Stage issue: 16 x f32x4, flat-coalesced (wave = 1KB contiguous).
  const f32x4* xs = (const f32x4*)(x + (size_t)row0 * 512);
  f32x4 xrw[16];
#pragma unroll
  for (int i = 0; i < 16; ++i) xrw[i] = xs[i * 256 + tid];

  short8 bfr[4][4];
#pragma unroll
  for (int nt = 0; nt < 4; ++nt)
    bfr[0][nt] = load_b_pk(wp, (wid * 4 + nt) * 16 + 0, lane);

  // cvt + swizzled ds_write (8B units; XOR swz preserves 8B halves).
  const int srow = tid >> 7, scol = (tid & 127) * 8;
#pragma unroll
  for (int i = 0; i < 16; ++i) {
    uint2 w;
    w.x = pk2(xrw[i][0], xrw[i][1]);
    w.y = pk2(xrw[i][2], xrw[i][3]);
    *(uint2*)(smem + swzoff<1024>(2 * i + srow, scol)) = w;
  }
#pragma unroll
  for (int c = 1; c < 4; ++c)
#pragma unroll
    for (int nt = 0; nt < 4; ++nt)
      bfr[c][nt] = load_b_pk(wp, (wid * 4 + nt) * 16 + c, lane);

  f32x4 acc[2][4];
#pragma unroll
  for (int m = 0; m < 2; ++m)
#pragma unroll
    for (int n = 0; n < 4; ++n) acc[m][n] = (f32x4){0.f, 0.f, 0.f, 0.f};

  __syncthreads();  // XB fully staged

  // Free-run: 16 chunks, zero barriers, B 4-deep (r11-verbatim schedule).
#pragma unroll
  for (int kt = 0; kt < 16; ++kt) {
    short8 a0 = lds_a<1024>(XB, 0, kt * 32, lane);
    short8 a1 = lds_a<1024>(XB, 16, kt * 32, lane);
#pragma unroll
    for (int nt = 0; nt < 4; ++nt) {
      acc[0][nt] = MFMA16(a0, bfr[kt & 3][nt], acc[0][nt]);
      acc[1][nt] = MFMA16(a1, bfr[kt & 3][nt], acc[1][nt]);
    }
    if (kt + 4 < 16) {
#pragma unroll
      for (int nt = 0; nt < 4; ++nt)
        bfr[kt & 3][nt] = load_b_pk(wp, (wid * 4 + nt) * 16 + kt + 4, lane);
    }
    __builtin_amdgcn_sched_barrier(0);
  }

  float bv1[4];
#pragma unroll
  for (int n = 0; n < 4; ++n) bv1[n] = b1[wid * 64 + n * 16 + lc];

  __syncthreads();  // all XB reads done before H1 overlays

  // Epilogue: bias + sigmoid -> H1 (swizzled image)
#pragma unroll
  for (int n = 0; n < 4; ++n) {
    const int ncol = wid * 64 + n * 16;
#pragma unroll
    for (int m = 0; m < 2; ++m)
#pragma unroll
      for (int i = 0; i < 4; ++i) {
        float v = fast_sigmoid(acc[m][n][i] + bv1[n]);
        *(uint16_t*)((char*)H1 + swzoff<512>(m * 16 + lr + i, (ncol + lc) * 2)) = f2bf(v);
      }
  }
  __syncthreads();  // H1 complete

  // Page out: 16KB swizzled image, 4 x 16B per thread, fully coalesced.
  u32x4* dst = (u32x4*)(h1g + (size_t)blockIdx.x * 16384);
  const u32x4* srcv = (const u32x4*)smem;
#pragma unroll
  for (int i = 0; i < 4; ++i) dst[i * 256 + tid] = srcv[i * 256 + tid];
}

// Kernel B: L2-L5. Restage h1 page (byte-identical), then r11 tail with
// fully disjoint H buffers (one fewer barrier).
__global__ __launch_bounds__(256, 3) void tail_kernel(
    const float* __restrict__ x, const char* __restrict__ h1g,
    const float* __restrict__ b2, const float* __restrict__ b3,
    const float* __restrict__ b4, const float* __restrict__ b5,
    const char* __restrict__ wp, float* __restrict__ out) {
  // Arena 30KB, all disjoint:
  //   H1 [0,16K), H2 [16K,24K), H3 [24K,28K), H4 [28K,30K)
  __shared__ __align__(16) char smem[30 * 1024];
  uint16_t* H1 = (uint16_t*)smem;                // [32][256] bf16, RB=512
  uint16_t* H2 = (uint16_t*)(smem + 16 * 1024);  // [32][128] bf16, RB=256
  uint16_t* H3 = (uint16_t*)(smem + 24 * 1024);  // [32][64]  bf16, RB=128
  uint16_t* H4 = (uint16_t*)(smem + 28 * 1024);  // [32][32]  bf16, RB=64

  const int tid = threadIdx.x;
  const int lane = tid & 63;
  const int wid = tid >> 6;
  const int row0 = blockIdx.x * 32;
  const int lr = (lane >> 4) << 2;
  const int lc = lane & 15;

  // Restage h1 page: 4 x 16B per thread, coalesced.
  {
    u32x4* d = (u32x4*)smem;
    const u32x4* s = (const u32x4*)(h1g + (size_t)blockIdx.x * 16384);
#pragma unroll
    for (int i = 0; i < 4; ++i) d[i * 256 + tid] = s[i * 256 + tid];
  }
  // Hoist L2 weights (overlaps the staging drain).
  short8 bfr2[2][8];
#pragma unroll
  for (int n = 0; n < 2; ++n)
#pragma unroll
    for (int kt = 0; kt < 8; ++kt)
      bfr2[n][kt] = load_b_pk(wp, 256 + (wid * 2 + n) * 8 + kt, lane);

  // in_size = count_nonzero(x[0])
  int in_size = 0;
#pragma unroll
  for (int j = 0; j < 8; ++j) {
    float v = x[j * 64 + lane];
    in_size += (int)__popcll(__ballot(v != 0.f));
  }

  __syncthreads();  // H1 staged

  // ---- Layer 2: h1[32x256] -> h2[32x128]; wave cols wid*32 (2 nt), 2 mt, KT=8
  f32x4 acc2[2][2];
#pragma unroll
  for (int m = 0; m < 2; ++m)
#pragma unroll
    for (int n = 0; n < 2; ++n) acc2[m][n] = (f32x4){0.f, 0.f, 0.f, 0.f};
#pragma unroll
  for (int m = 0; m < 2; ++m) {
#pragma unroll
    for (int kt = 0; kt < 8; ++kt) {
      short8 afr = lds_a<512>(H1, m * 16, kt * 32, lane);
      acc2[m][0] = MFMA16(afr, bfr2[0][kt], acc2[m][0]);
      acc2[m][1] = MFMA16(afr, bfr2[1][kt], acc2[m][1]);
    }
  }
  // Hoist L3 weights + L2 bias
  short8 bfr3[4];
#pragma unroll
  for (int kt = 0; kt < 4; ++kt)
    bfr3[kt] = load_b_pk(wp, 320 + wid * 4 + kt, lane);
  float bv2[2];
#pragma unroll
  for (int n = 0; n < 2; ++n) bv2[n] = b2[wid * 32 + n * 16 + lc];
  // H2 disjoint from H1: no pre-write barrier
#pragma unroll
  for (int n = 0; n < 2; ++n) {
    const int ncol = wid * 32 + n * 16;
#pragma unroll
    for (int m = 0; m < 2; ++m)
#pragma unroll
      for (int i = 0; i < 4; ++i) {
        float v = fast_sigmoid(acc2[m][n][i] + bv2[n]);
        *(uint16_t*)((char*)H2 + swzoff<256>(m * 16 + lr + i, (ncol + lc) * 2)) = f2bf(v);
      }
  }
  __syncthreads();

  // ---- Layer 3: h2[32x128] -> h3[32x64]; wave col-tile wid (1 nt), 2 mt, KT=4
  f32x4 acc3[2];
#pragma unroll
  for (int m = 0; m < 2; ++m) acc3[m] = (f32x4){0.f, 0.f, 0.f, 0.f};
#pragma unroll
  for (int m = 0; m < 2; ++m)
#pragma unroll
    for (int kt = 0; kt < 4; ++kt) {
      short8 afr = lds_a<256>(H2, m * 16, kt * 32, lane);
      acc3[m] = MFMA16(afr, bfr3[kt], acc3[m]);
    }
  // Hoist L4 weights + L3 bias
  short8 bfr4[2];
#pragma unroll
  for (int kt = 0; kt < 2; ++kt)
    bfr4[kt] = load_b_pk(wp, 336 + (wid & 1) * 2 + kt, lane);
  const float bv3 = b3[wid * 16 + lc];
#pragma unroll
  for (int m = 0; m < 2; ++m)
#pragma unroll
    for (int i = 0; i < 4; ++i) {
      float v = fast_sigmoid(acc3[m][i] + bv3);
      *(uint16_t*)((char*)H3 + swzoff<128>(m * 16 + lr + i, (wid * 16 + lc) * 2)) = f2bf(v);
    }
  __syncthreads();

  // ---- Layer 4: h3[32x64] -> h4[32x32]; waves 2x2: rows wm*16, col wn*16, KT=2
  const int wm = wid >> 1, wn = wid & 1;
  f32x4 acc4 = (f32x4){0.f, 0.f, 0.f, 0.f};
#pragma unroll
  for (int kt = 0; kt < 2; ++kt) {
    short8 afr = lds_a<128>(H3, wm * 16, kt * 32, lane);
    acc4 = MFMA16(afr, bfr4[kt], acc4);
  }
  // Hoist L5 weights + L4/L5 bias
  short8 bfr5[8];
#pragma unroll
  for (int nt = 0; nt < 8; ++nt)
    bfr5[nt] = load_b_pk(wp, 340 + wid * 8 + nt, lane);
  const float bv4 = b4[wn * 16 + lc];
  float bv5[8];
#pragma unroll
  for (int nt = 0; nt < 8; ++nt) bv5[nt] = b5[wid * 128 + nt * 16 + lc];
#pragma unroll
  for (int i = 0; i < 4; ++i) {
    float v = fast_sigmoid(acc4[i] + bv4);
    *(uint16_t*)((char*)H4 + swzoff<64>(wm * 16 + lr + i, (wn * 16 + lc) * 2)) = f2bf(v);
  }
  __syncthreads();

  // ---- Layer 5: h4[32x32] -> out[32x512]; wave cols wid*128 (8 nt), 2 mt, KT=1
#pragma unroll
  for (int m = 0; m < 2; ++m) {
    short8 afr = lds_a<64>(H4, m * 16, 0, lane);
#pragma unroll
    for (int nt = 0; nt < 8; ++nt) {
      f32x4 av = MFMA16(afr, bfr5[nt], ((f32x4){0.f, 0.f, 0.f, 0.f}));
      const int col = wid * 128 + nt * 16 + lc;
      const bool keep = col < in_size;
#pragma unroll
      for (int i = 0; i < 4; ++i) {
        float v = keep ? (av[i] + bv5[nt]) : 0.f;
        out[(size_t)(row0 + m * 16 + lr + i) * 512 + col] = v;
      }
    }
  }
}

// ============================================================================
// FUSED PATH — r11 verbatim (best fused @73.25us); fallback when ws is small.
// ============================================================================
template <bool P>
__global__ __launch_bounds__(256, 3) void mlp5_kernel(
    const float* __restrict__ x,
    const float* __restrict__ w1, const float* __restrict__ b1,
    const float* __restrict__ w2, const float* __restrict__ b2,
    const float* __restrict__ w3, const float* __restrict__ b3,
    const float* __restrict__ w4, const float* __restrict__ b4,
    const float* __restrict__ w5, const float* __restrict__ b5,
    const char* __restrict__ wp, float* __restrict__ out) {
  __shared__ __align__(16) char smem[32 * 1024];
  uint16_t* XB = (uint16_t*)smem;
  uint16_t* H1 = (uint16_t*)smem;
  uint16_t* H2 = (uint16_t*)smem;
  uint16_t* H3 = (uint16_t*)(smem + 8 * 1024);
  uint16_t* H4 = (uint16_t*)(smem + 12 * 1024);

  const int tid = threadIdx.x;
  const int lane = tid & 63;
  const int wid = tid >> 6;
  const int row0 = blockIdx.x * 32;
  const int lr = (lane >> 4) << 2;
  const int lc = lane & 15;

  const f32x4* xs = (const f32x4*)(x + (size_t)row0 * 512);
  f32x4 xrw[16];
#pragma unroll
  for (int i = 0; i < 16; ++i) xrw[i] = xs[i * 256 + tid];

  short8 bfr[4][4];
#pragma unroll
  for (int nt = 0; nt < 4; ++nt)
    bfr[0][nt] = bfrag<P>(wp, w1, 512, 0, wid * 4 + nt, 16, 0, lane);

  int in_size = 0;
#pragma unroll
  for (int j = 0; j < 8; ++j) {
    float v = x[j * 64 + lane];
    in_size += (int)__popcll(__ballot(v != 0.f));
  }

  const int srow = tid >> 7, scol = (tid & 127) * 8;
#pragma unroll
  for (int i = 0; i < 16; ++i) {
    uint2 w;
    w.x = pk2(xrw[i][0], xrw[i][1]);
    w.y = pk2(xrw[i][2], xrw[i][3]);
    *(uint2*)(smem + swzoff<1024>(2 * i + srow, scol)) = w;
  }
#pragma unroll
  for (int c = 1; c < 4; ++c)
#pragma unroll
    for (int nt = 0; nt < 4; ++nt)
      bfr[c][nt] = bfrag<P>(wp, w1, 512, 0, wid * 4 + nt, 16, c, lane);

  f32x4 acc[2][4];
#pragma unroll
  for (int m = 0; m < 2; ++m)
#pragma unroll
    for (int n = 0; n < 4; ++n) acc[m][n] = (f32x4){0.f, 0.f, 0.f, 0.f};

  __syncthreads();

#pragma unroll
  for (int kt = 0; kt < 16; ++kt) {
    short8 a0 = lds_a<1024>(XB, 0, kt * 32, lane);
    short8 a1 = lds_a<1024>(XB, 16, kt * 32, lane);
#pragma unroll
    for (int nt = 0; nt < 4; ++nt) {
      acc[0][nt] = MFMA16(a0, bfr[kt & 3][nt], acc[0][nt]);
      acc[1][nt] = MFMA16(a1, bfr[kt & 3][nt], acc[1][nt]);
    }
    if (kt + 4 < 16) {
#pragma unroll
      for (int nt = 0; nt < 4; ++nt)
        bfr[kt & 3][nt] = bfrag<P>(wp, w1, 512, 0, wid * 4 + nt, 16, kt + 4, lane);
    }
    __builtin_amdgcn_sched_barrier(0);
  }

  short8 bfr2[2][8];
#pragma unroll
  for (int n = 0; n < 2; ++n)
#pragma unroll
    for (int kt = 0; kt < 8; ++kt)
      bfr2[n][kt] = bfrag<P>(wp, w2, 256, 256, wid * 2 + n, 8, kt, lane);
  float bv1[4];
#pragma unroll
  for (int n = 0; n < 4; ++n) bv1[n] = b1[wid * 64 + n * 16 + lc];

  __syncthreads();

#pragma unroll
  for (int n = 0; n < 4; ++n) {
    const int ncol = wid * 64 + n * 16;
#pragma unroll
    for (int m = 0; m < 2; ++m)
#pragma unroll
      for (int i = 0; i < 4; ++i) {
        float v = fast_sigmoid(acc[m][n][i] + bv1[n]);
        *(uint16_t*)((char*)H1 + swzoff<512>(m * 16 + lr + i, (ncol + lc) * 2)) = f2bf(v);
      }
  }
  __syncthreads();

  {
    f32x4 acc2[2][2];
#pragma unroll
    for (int m = 0; m < 2; ++m)
#pragma unroll
      for (int n = 0; n < 2; ++n) acc2[m][n] = (f32x4){0.f, 0.f, 0.f, 0.f};
#pragma unroll
    for (int m = 0; m < 2; ++m) {
#pragma unroll
      for (int kt = 0; kt < 8; ++kt) {
        short8 afr = lds_a<512>(H1, m * 16, kt * 32, lane);
        acc2[m][0] = MFMA16(afr, bfr2[0][kt], acc2[m][0]);
        acc2[m][1] = MFMA16(afr, bfr2[1][kt], acc2[m][1]);
      }
    }
    short8 bfr3[4];
#pragma unroll
    for (int kt = 0; kt < 4; ++kt)
      bfr3[kt] = bfrag<P>(wp, w3, 128, 320, wid, 4, kt, lane);
    float bv2[2];
#pragma unroll
    for (int n = 0; n < 2; ++n) bv2[n] = b2[wid * 32 + n * 16 + lc];
    __syncthreads();
#pragma unroll
    for (int n = 0; n < 2; ++n) {
      const int ncol = wid * 32 + n * 16;
#pragma unroll
      for (int m = 0; m < 2; ++m)
#pragma unroll
        for (int i = 0; i < 4; ++i) {
          float v = fast_sigmoid(acc2[m][n][i] + bv2[n]);
          *(uint16_t*)((char*)H2 + swzoff<256>(m * 16 + lr + i, (ncol + lc) * 2)) = f2bf(v);
        }
    }
    __syncthreads();

    f32x4 acc3[2];
#pragma unroll
    for (int m = 0; m < 2; ++m) acc3[m] = (f32x4){0.f, 0.f, 0.f, 0.f};
#pragma unroll
    for (int m = 0; m < 2; ++m)
#pragma unroll
      for (int kt = 0; kt < 4; ++kt) {
        short8 afr = lds_a<256>(H2, m * 16, kt * 32, lane);
        acc3[m] = MFMA16(afr, bfr3[kt], acc3[m]);
      }
    short8 bfr4[2];
#pragma unroll
    for (int kt = 0; kt < 2; ++kt)
      bfr4[kt] = bfrag<P>(wp, w4, 64, 336, wid & 1, 2, kt, lane);
    const float bv3 = b3[wid * 16 + lc];
    {
#pragma unroll
      for (int m = 0; m < 2; ++m)
#pragma unroll
        for (int i = 0; i < 4; ++i) {
          float v = fast_sigmoid(acc3[m][i] + bv3);
          *(uint16_t*)((char*)H3 + swzoff<128>(m * 16 + lr + i, (wid * 16 + lc) * 2)) = f2bf(v);
        }
    }
    __syncthreads();

    const int wm = wid >> 1, wn = wid & 1;
    f32x4 acc4 = (f32x4){0.f, 0.f, 0.f, 0.f};
#pragma unroll
    for (int kt = 0; kt < 2; ++kt) {
      short8 afr = lds_a<128>(H3, wm * 16, kt * 32, lane);
      acc4 = MFMA16(afr, bfr4[kt], acc4);
    }
    short8 bfr5[8];
#pragma unroll
    for (int nt = 0; nt < 8; ++nt)
      bfr5[nt] = bfrag<P>(wp, w5, 32, 340, wid * 8 + nt, 1, 0, lane);
    const float bv4 = b4[wn * 16 + lc];
    float bv5[8];
#pragma unroll
    for (int nt = 0; nt < 8; ++nt) bv5[nt] = b5[wid * 128 + nt * 16 + lc];
    {
#pragma unroll
      for (int i = 0; i < 4; ++i) {
        float v = fast_sigmoid(acc4[i] + bv4);
        *(uint16_t*)((char*)H4 + swzoff<64>(wm * 16 + lr + i, (wn * 16 + lc) * 2)) = f2bf(v);
      }
    }
    __syncthreads();

#pragma unroll
    for (int m = 0; m < 2; ++m) {
      short8 afr = lds_a<64>(H4, m * 16, 0, lane);
#pragma unroll
      for (int nt = 0; nt < 8; ++nt) {
        f32x4 av = MFMA16(afr, bfr5[nt], ((f32x4){0.f, 0.f, 0.f, 0.f}));
        const int col = wid * 128 + nt * 16 + lc;
        const bool keep = col < in_size;
#pragma unroll
        for (int i = 0; i < 4; ++i) {
          float v = keep ? (av[i] + bv5[nt]) : 0.f;
          out[(size_t)(row0 + m * 16 + lr + i) * 512 + col] = v;
        }
      }
    }
  }
}

extern "C" void kernel_launch(void* const* d_in, const int* in_sizes, int n_in,
                              void* d_out, int out_size, void* d_ws, size_t ws_size,
                              hipStream_t stream) {
  const float* x  = (const float*)d_in[0];
  const float* w1 = (const float*)d_in[1];
  const float* b1 = (const float*)d_in[2];
  const float* w2 = (const float*)d_in[3];
  const float* b2 = (const float*)d_in[4];
  const float* w3 = (const float*)d_in[5];
  const float* b3 = (const float*)d_in[6];
  const float* w4 = (const float*)d_in[7];
  const float* b4 = (const float*)d_in[8];
  const float* w5 = (const float*)d_in[9];
  const float* b5 = (const float*)d_in[10];
  float* out = (float*)d_out;

  dim3 grid(65536 / 32);
  dim3 block(256);
  const size_t H1G_OFF = 512 * 1024;
  const size_t H1G_BYTES = (size_t)2048 * 16384;  // 32 MB
  const bool packed = ws_size >= (size_t)(372 * 1024);
  const bool split = ws_size >= H1G_OFF + H1G_BYTES;
  if (split) {
    pack_kernel<<<372, 64, 0, stream>>>(w1, w2, w3, w4, w5, (char*)d_ws);
    char* h1g = (char*)d_ws + H1G_OFF;
    l1_kernel<<<grid, block, 0, stream>>>(x, b1, (const char*)d_ws, h1g);
    tail_kernel<<<grid, block, 0, stream>>>(x, h1g, b2, b3, b4, b5,
                                            (const char*)d_ws, out);
  } else if (packed) {
    pack_kernel<<<372, 64, 0, stream>>>(w1, w2, w3, w4, w5, (char*)d_ws);
    mlp5_kernel<true><<<grid, block, 0, stream>>>(x, w1, b1, w2, b2, w3, b3, w4, b4,
                                                  w5, b5, (const char*)d_ws, out);
  } else {
    mlp5_kernel<false><<<grid, block, 0, stream>>>(x, w1, b1, w2, b2, w3, b3, w4, b4,
                                                   w5, b5, nullptr, out);
  }
}

// Round 13
// 73.174 us; speedup vs baseline: 1.1726x; 1.1726x over previous
//
#include <hip/hip_runtime.h>
#include <hip/hip_bf16.h>
#include <stdint.h>

typedef __attribute__((ext_vector_type(4))) float f32x4;
typedef __attribute__((ext_vector_type(4))) unsigned int u32x4;
typedef __attribute__((ext_vector_type(8))) short short8;

#define MFMA16(a, b, c) __builtin_amdgcn_mfma_f32_16x16x32_bf16((a), (b), (c), 0, 0, 0)

__device__ __forceinline__ uint16_t f2bf(float f) {
  __hip_bfloat16 h = __float2bfloat16(f);
  return __builtin_bit_cast(uint16_t, h);
}

// v_rcp_f32-based sigmoid: rcp rel-err ~1ulp << bf16 rounding of every consumer.
__device__ __forceinline__ float fast_sigmoid(float v) {
  return __builtin_amdgcn_rcpf(1.f + __expf(-v));
}

__device__ __forceinline__ short8 cvt8(f32x4 a, f32x4 b) {
  short8 r;
  r[0] = (short)f2bf(a[0]); r[1] = (short)f2bf(a[1]);
  r[2] = (short)f2bf(a[2]); r[3] = (short)f2bf(a[3]);
  r[4] = (short)f2bf(b[0]); r[5] = (short)f2bf(b[1]);
  r[6] = (short)f2bf(b[2]); r[7] = (short)f2bf(b[3]);
  return r;
}

__device__ __forceinline__ uint32_t pk2(float a, float b) {
  return (uint32_t)f2bf(a) | ((uint32_t)f2bf(b) << 16);
}

// XOR-swizzled byte offset into row-major [rows][RB bytes] LDS tile (16B slots).
template <int RB>
__device__ __forceinline__ int swzoff(int row, int bcol) {
  constexpr int SLM = (((RB / 16) < 8 ? (RB / 16) : 8)) - 1;
  return row * RB + (bcol ^ ((row & SLM) << 4));
}

// A-fragment (16x32 bf16) from swizzled bf16 LDS tile.
template <int RB>
__device__ __forceinline__ short8 lds_a(const uint16_t* buf, int row0, int k0, int lane) {
  int r = row0 + (lane & 15);
  int bcol = (k0 + ((lane >> 4) << 3)) * 2;
  u32x4 raw = *(const u32x4*)((const char*)buf + swzoff<RB>(r, bcol));
  return __builtin_bit_cast(short8, raw);
}

// Fragment from row-major fp32 M[ld] (coalesced 16-row pattern)
__device__ __forceinline__ short8 load_frag_f32(const float* M, int ld, int r0, int k0, int lane) {
  const float* p = M + (size_t)(r0 + (lane & 15)) * ld + (k0 + ((lane >> 4) << 3));
  f32x4 a = *(const f32x4*)p;
  f32x4 b = *(const f32x4*)(p + 4);
  return cvt8(a, b);
}

// Packed-path B-fragment: one coalesced 16B load from pre-packed d_ws
__device__ __forceinline__ short8 load_b_pk(const char* base, int f, int lane) {
  u32x4 raw = *(const u32x4*)(base + (((size_t)f * 64 + lane) << 4));
  return __builtin_bit_cast(short8, raw);
}

template <bool P>
__device__ __forceinline__ short8 bfrag(const char* wp, const float* W, int K,
                                        int f0, int ntg, int KT, int kt, int lane) {
  if constexpr (P) {
    return load_b_pk(wp, f0 + ntg * KT + kt, lane);
  } else {
    return load_frag_f32(W, K, ntg * 16, kt * 32, lane);
  }
}

// ---- weight pre-pack: 372 fragments x (64 lanes x 16B) = 372 KB in d_ws ----
__global__ void pack_kernel(const float* __restrict__ w1, const float* __restrict__ w2,
                            const float* __restrict__ w3, const float* __restrict__ w4,
                            const float* __restrict__ w5, char* __restrict__ ws) {
  int b = blockIdx.x, lane = threadIdx.x;
  const float* W;
  int K, f0;
  if (b < 256)      { W = w1; K = 512; f0 = 0; }
  else if (b < 320) { W = w2; K = 256; f0 = 256; }
  else if (b < 336) { W = w3; K = 128; f0 = 320; }
  else if (b < 340) { W = w4; K = 64;  f0 = 336; }
  else              { W = w5; K = 32;  f0 = 340; }
  int f = b - f0;
  int KT = K / 32;
  int nt = f / KT, kt = f % KT;
  short8 r = load_frag_f32(W, K, nt * 16, kt * 32, lane);
  *(u32x4*)(ws + (((size_t)b * 64 + lane) << 4)) = __builtin_bit_cast(u32x4, r);
}

// 32 rows/block, 256 threads, 2048 blocks. (r11 structure — best @73.25us.)
// L1 = ONE-SHOT STAGE + FREE-RUN: whole 32x512 x-tile staged to a 32KB
// XOR-swizzled bf16 LDS tile (16 coalesced f32x4 loads/thread, one exposed
// HBM latency per block), ONE __syncthreads, then 16 K-chunks of pure
// {2 ds_read_b128 + 8 MFMA} with ZERO barriers. B frags rotate through 4
// slots issued 4 chunks ahead (~3.7 iter cover >= L2 latency).
// Family closed: convoy staging (r0-6) ~76; same-wave/LDS-free (r7/8) 110+;
// 16-row TLP (r10) 86.7; kernel split (r12) 85.8 (ws memset + h1 roundtrip).
// (256,3): VGPR cap 168; 76 live, no spill.
template <bool P>
__global__ __launch_bounds__(256, 3) void mlp5_kernel(
    const float* __restrict__ x,
    const float* __restrict__ w1, const float* __restrict__ b1,
    const float* __restrict__ w2, const float* __restrict__ b2,
    const float* __restrict__ w3, const float* __restrict__ b3,
    const float* __restrict__ w4, const float* __restrict__ b4,
    const float* __restrict__ w5, const float* __restrict__ b5,
    const char* __restrict__ wp, float* __restrict__ out) {
  // Arena 32KB (every overlay is protected by a barrier):
  //   L1: XB [32][1024B] swizzled bf16 x-tile, [0,32K)
  //   L1 epilogue (after syncthreads): H1 [0,16K) overlays XB
  //   L2: H1 in; H2 [0,8K) out (after the barrier following last H1 read)
  //   L3: H2 in, H3 [8K,12K) out
  //   L4: H3 in, H4 [12K,14K) out
  //   L5: H4 in
  __shared__ __align__(16) char smem[32 * 1024];
  uint16_t* XB = (uint16_t*)smem;                // [32][512] bf16, RB=1024
  uint16_t* H1 = (uint16_t*)smem;                // [32][256] bf16, RB=512
  uint16_t* H2 = (uint16_t*)smem;                // [32][128] bf16, RB=256
  uint16_t* H3 = (uint16_t*)(smem + 8 * 1024);   // [32][64]  bf16, RB=128
  uint16_t* H4 = (uint16_t*)(smem + 12 * 1024);  // [32][32]  bf16, RB=64

  const int tid = threadIdx.x;
  const int lane = tid & 63;
  const int wid = tid >> 6;
  const int row0 = blockIdx.x * 32;
  const int lr = (lane >> 4) << 2;
  const int lc = lane & 15;

  // ---- L1 stage issue: 16 x f32x4, flat-coalesced (wave = 1KB contiguous).
  // Load i covers row 2i+(tid>>7), float cols (tid&127)*4..+4.
  const f32x4* xs = (const f32x4*)(x + (size_t)row0 * 512);
  f32x4 xrw[16];
#pragma unroll
  for (int i = 0; i < 16; ++i) xrw[i] = xs[i * 256 + tid];

  // B frags for chunk 0 issued early (L2-hot; lands under the stage drain).
  short8 bfr[4][4];
#pragma unroll
  for (int nt = 0; nt < 4; ++nt)
    bfr[0][nt] = bfrag<P>(wp, w1, 512, 0, wid * 4 + nt, 16, 0, lane);

  // in_size = count_nonzero(x[0])
  int in_size = 0;
#pragma unroll
  for (int j = 0; j < 8; ++j) {
    float v = x[j * 64 + lane];
    in_size += (int)__popcll(__ballot(v != 0.f));
  }

  // ---- cvt + swizzled ds_write (8B per load; XOR swz preserves 8B halves).
  // Element [r][k] lands at r*1024 + (2k ^ ((r&7)<<4)) — matches lds_a<1024>.
  const int srow = tid >> 7, scol = (tid & 127) * 8;
#pragma unroll
  for (int i = 0; i < 16; ++i) {
    uint2 w;
    w.x = pk2(xrw[i][0], xrw[i][1]);
    w.y = pk2(xrw[i][2], xrw[i][3]);
    *(uint2*)(smem + swzoff<1024>(2 * i + srow, scol)) = w;
  }
  // B frags for chunks 1-3 (post-stores: xrw regs dead -> peak live ~100).
#pragma unroll
  for (int c = 1; c < 4; ++c)
#pragma unroll
    for (int nt = 0; nt < 4; ++nt)
      bfr[c][nt] = bfrag<P>(wp, w1, 512, 0, wid * 4 + nt, 16, c, lane);

  f32x4 acc[2][4];
#pragma unroll
  for (int m = 0; m < 2; ++m)
#pragma unroll
    for (int n = 0; n < 4; ++n) acc[m][n] = (f32x4){0.f, 0.f, 0.f, 0.f};

  __syncthreads();  // the ONLY L1 barrier: XB fully staged

  // ---- Layer 1 free-run: x[32x512] @ w1[256x512]^T -> acc, no barriers.
  // Per kt: 2 ds_read_b128 (conflict-free swizzle) + 8 MFMA; B slot kt&3
  // reloaded with chunk kt+4 right after its last use (~3.7 iter cover).
#pragma unroll
  for (int kt = 0; kt < 16; ++kt) {
    short8 a0 = lds_a<1024>(XB, 0, kt * 32, lane);
    short8 a1 = lds_a<1024>(XB, 16, kt * 32, lane);
#pragma unroll
    for (int nt = 0; nt < 4; ++nt) {
      acc[0][nt] = MFMA16(a0, bfr[kt & 3][nt], acc[0][nt]);
      acc[1][nt] = MFMA16(a1, bfr[kt & 3][nt], acc[1][nt]);
    }
    if (kt + 4 < 16) {
#pragma unroll
      for (int nt = 0; nt < 4; ++nt)
        bfr[kt & 3][nt] = bfrag<P>(wp, w1, 512, 0, wid * 4 + nt, 16, kt + 4, lane);
    }
    // Pin iteration boundaries (prevents whole-loop load hoisting / spills).
    __builtin_amdgcn_sched_barrier(0);
  }

  // Hoist L2 weights + L1 bias (latency hides under barrier + epilogue VALU)
  short8 bfr2[2][8];
#pragma unroll
  for (int n = 0; n < 2; ++n)
#pragma unroll
    for (int kt = 0; kt < 8; ++kt)
      bfr2[n][kt] = bfrag<P>(wp, w2, 256, 256, wid * 2 + n, 8, kt, lane);
  float bv1[4];
#pragma unroll
  for (int n = 0; n < 4; ++n) bv1[n] = b1[wid * 64 + n * 16 + lc];

  __syncthreads();  // all XB reads done before H1 overlays [0,16K)

  // L1 epilogue: bias + sigmoid -> H1
#pragma unroll
  for (int n = 0; n < 4; ++n) {
    const int ncol = wid * 64 + n * 16;
#pragma unroll
    for (int m = 0; m < 2; ++m)
#pragma unroll
      for (int i = 0; i < 4; ++i) {
        float v = fast_sigmoid(acc[m][n][i] + bv1[n]);
        *(uint16_t*)((char*)H1 + swzoff<512>(m * 16 + lr + i, (ncol + lc) * 2)) = f2bf(v);
      }
  }
  __syncthreads();

  // ---- Layer 2: h1[32x256] -> h2[32x128]; wave cols wid*32 (2 nt), 2 mt, KT=8
  {
    f32x4 acc2[2][2];
#pragma unroll
    for (int m = 0; m < 2; ++m)
#pragma unroll
      for (int n = 0; n < 2; ++n) acc2[m][n] = (f32x4){0.f, 0.f, 0.f, 0.f};
#pragma unroll
    for (int m = 0; m < 2; ++m) {
#pragma unroll
      for (int kt = 0; kt < 8; ++kt) {
        short8 afr = lds_a<512>(H1, m * 16, kt * 32, lane);
        acc2[m][0] = MFMA16(afr, bfr2[0][kt], acc2[m][0]);
        acc2[m][1] = MFMA16(afr, bfr2[1][kt], acc2[m][1]);
      }
    }
    // Hoist L3 weights + L2 bias
    short8 bfr3[4];
#pragma unroll
    for (int kt = 0; kt < 4; ++kt)
      bfr3[kt] = bfrag<P>(wp, w3, 128, 320, wid, 4, kt, lane);
    float bv2[2];
#pragma unroll
    for (int n = 0; n < 2; ++n) bv2[n] = b2[wid * 32 + n * 16 + lc];
    __syncthreads();  // REQUIRED: last H1 read done before H2 overlays [0,8K)
#pragma unroll
    for (int n = 0; n < 2; ++n) {
      const int ncol = wid * 32 + n * 16;
#pragma unroll
      for (int m = 0; m < 2; ++m)
#pragma unroll
        for (int i = 0; i < 4; ++i) {
          float v = fast_sigmoid(acc2[m][n][i] + bv2[n]);
          *(uint16_t*)((char*)H2 + swzoff<256>(m * 16 + lr + i, (ncol + lc) * 2)) = f2bf(v);
        }
    }
    __syncthreads();

    // ---- Layer 3: h2[32x128] -> h3[32x64]; wave col-tile wid (1 nt), 2 mt, KT=4
    f32x4 acc3[2];
#pragma unroll
    for (int m = 0; m < 2; ++m) acc3[m] = (f32x4){0.f, 0.f, 0.f, 0.f};
#pragma unroll
    for (int m = 0; m < 2; ++m)
#pragma unroll
      for (int kt = 0; kt < 4; ++kt) {
        short8 afr = lds_a<256>(H2, m * 16, kt * 32, lane);
        acc3[m] = MFMA16(afr, bfr3[kt], acc3[m]);
      }
    // Hoist L4 weights + L3 bias
    short8 bfr4[2];
#pragma unroll
    for (int kt = 0; kt < 2; ++kt)
      bfr4[kt] = bfrag<P>(wp, w4, 64, 336, wid & 1, 2, kt, lane);
    const float bv3 = b3[wid * 16 + lc];
    // H3 [8K,12K) disjoint from H2 [0,8K): no barrier needed before write
    {
#pragma unroll
      for (int m = 0; m < 2; ++m)
#pragma unroll
        for (int i = 0; i < 4; ++i) {
          float v = fast_sigmoid(acc3[m][i] + bv3);
          *(uint16_t*)((char*)H3 + swzoff<128>(m * 16 + lr + i, (wid * 16 + lc) * 2)) = f2bf(v);
        }
    }
    __syncthreads();

    // ---- Layer 4: h3[32x64] -> h4[32x32]; waves 2x2: rows wm*16, col wn*16, KT=2
    const int wm = wid >> 1, wn = wid & 1;
    f32x4 acc4 = (f32x4){0.f, 0.f, 0.f, 0.f};
#pragma unroll
    for (int kt = 0; kt < 2; ++kt) {
      short8 afr = lds_a<128>(H3, wm * 16, kt * 32, lane);
      acc4 = MFMA16(afr, bfr4[kt], acc4);
    }
    // Hoist L5 weights + L4/L5 bias
    short8 bfr5[8];
#pragma unroll
    for (int nt = 0; nt < 8; ++nt)
      bfr5[nt] = bfrag<P>(wp, w5, 32, 340, wid * 8 + nt, 1, 0, lane);
    const float bv4 = b4[wn * 16 + lc];
    float bv5[8];
#pragma unroll
    for (int nt = 0; nt < 8; ++nt) bv5[nt] = b5[wid * 128 + nt * 16 + lc];
    // H4 [12K,14K) disjoint from H3 reads: no barrier needed before write
    {
#pragma unroll
      for (int i = 0; i < 4; ++i) {
        float v = fast_sigmoid(acc4[i] + bv4);
        *(uint16_t*)((char*)H4 + swzoff<64>(wm * 16 + lr + i, (wn * 16 + lc) * 2)) = f2bf(v);
      }
    }
    __syncthreads();

    // ---- Layer 5: h4[32x32] -> out[32x512]; wave cols wid*128 (8 nt), 2 mt, KT=1
#pragma unroll
    for (int m = 0; m < 2; ++m) {
      short8 afr = lds_a<64>(H4, m * 16, 0, lane);
#pragma unroll
      for (int nt = 0; nt < 8; ++nt) {
        f32x4 av = MFMA16(afr, bfr5[nt], ((f32x4){0.f, 0.f, 0.f, 0.f}));
        const int col = wid * 128 + nt * 16 + lc;
        const bool keep = col < in_size;
#pragma unroll
        for (int i = 0; i < 4; ++i) {
          float v = keep ? (av[i] + bv5[nt]) : 0.f;
          out[(size_t)(row0 + m * 16 + lr + i) * 512 + col] = v;
        }
      }
    }
  }
}

extern "C" void kernel_launch(void* const* d_in, const int* in_sizes, int n_in,
                              void* d_out, int out_size, void* d_ws, size_t ws_size,
                              hipStream_t stream) {
  const float* x  = (const float*)d_in[0];
  const float* w1 = (const float*)d_in[1];
  const float* b1 = (const float*)d_in[2];
  const float* w2 = (const float*)d_in[3];
  const float* b2 = (const float*)d_in[4];
  const float* w3 = (const float*)d_in[5];
  const float* b3 = (const float*)d_in[6];
  const float* w4 = (const float*)d_in[7];
  const float* b4 = (const float*)d_in[8];
  const float* w5 = (const float*)d_in[9];
  const float* b5 = (const float*)d_in[10];
  float* out = (float*)d_out;

  dim3 grid(65536 / 32);
  dim3 block(256);
  const bool packed = ws_size >= (size_t)(372 * 1024);
  if (packed) {
    pack_kernel<<<372, 64, 0, stream>>>(w1, w2, w3, w4, w5, (char*)d_ws);
    mlp5_kernel<true><<<grid, block, 0, stream>>>(x, w1, b1, w2, b2, w3, b3, w4, b4,
                                                  w5, b5, (const char*)d_ws, out);
  } else {
    mlp5_kernel<false><<<grid, block, 0, stream>>>(x, w1, b1, w2, b2, w3, b3, w4, b4,
                                                   w5, b5, nullptr, out);
  }
}